// Round 2
// baseline (4926.136 us; speedup 1.0000x reference)
//
#include <hip/hip_runtime.h>
#include <hip/hip_cooperative_groups.h>

namespace cg = cooperative_groups;

typedef short bfv8 __attribute__((ext_vector_type(8)));  // 8 x bf16 (4 VGPRs)
typedef float fv4  __attribute__((ext_vector_type(4)));  // 4 x f32 accum

#define T_STEPS 128
#define BATCH   64
#define FDIM    512
#define HDIM    1024
#define NCOL    4096   // 4*HDIM, gate-interleaved: n = j*4 + g (g: 0=f,1=i,2=o,3=c)
#define NCLS    513

static __device__ __forceinline__ float b2f(unsigned short u) {
  union { unsigned int i; float f; } v; v.i = ((unsigned int)u) << 16; return v.f;
}
static __device__ __forceinline__ unsigned short f2b(float f) {
  union { float f; unsigned int i; } v; v.f = f;
  unsigned int r = v.i + 0x7FFFu + ((v.i >> 16) & 1u);   // RNE
  return (unsigned short)(r >> 16);
}
static __device__ __forceinline__ float sigm(float x) { return 1.0f / (1.0f + __expf(-x)); }
static __device__ __forceinline__ float tanh_f(float x) {
  float e = __expf(-2.0f * fabsf(x));
  float t = (1.0f - e) / (1.0f + e);
  return x >= 0.0f ? t : -t;
}

// ---- dtype detector: bf16 mode iff even-index ushorts look like bf16 N(0,1) ----
__global__ void detect_k(const unsigned short* __restrict__ xr, int* __restrict__ flag) {
  __shared__ int cnt;
  if (threadIdx.x == 0) cnt = 0;
  __syncthreads();
  int local = 0;
  for (int s = 0; s < 4; ++s) {
    int i = threadIdx.x + 256 * s;          // i in [0,1024)
    unsigned short u = xr[2 * i];           // even ushort
    int e = (u >> 7) & 0xFF;                // bf16 exponent field
    if (e >= 112 && e <= 131) local++;      // |x| in [2^-15, 32)
  }
  atomicAdd(&cnt, local);
  __syncthreads();
  if (threadIdx.x == 0) *flag = (cnt >= 512) ? 1 : 0;
}

// ---- x -> bf16 (copy or convert) ----
__global__ void convert_x_k(const void* __restrict__ x, const int* __restrict__ flagp,
                            unsigned short* __restrict__ xbf) {
  int idx = blockIdx.x * 256 + threadIdx.x;   // < T*B*F = 4194304 (exact grid)
  if (*flagp) xbf[idx] = ((const unsigned short*)x)[idx];
  else        xbf[idx] = f2b(((const float*)x)[idx]);
}

// Tessarine block table: comp = rb ^ cb ; sign = - iff (rb odd) && (cb even).
// WXT[n][k] = big[k][j] for gate g, n = j*4+g  (transposed big matrix, bf16)
__global__ void expand_x_k(const void* w0, const void* w1, const void* w2, const void* w3,
                           const int* __restrict__ flagp, unsigned short* __restrict__ WXT) {
  int idx = blockIdx.x * 256 + threadIdx.x;   // < NCOL*FDIM (exact grid)
  int n = idx >> 9, k = idx & 511;
  int j = n >> 2, g = n & 3;
  int rb = k >> 7, p = k & 127;               // FDIM/4 = 128
  int cb = j >> 8, q = j & 255;               // HDIM/4 = 256
  int comp = rb ^ cb;
  int neg = (rb & 1) && !(cb & 1);
  const void* W = (g == 0) ? w0 : (g == 1) ? w1 : (g == 2) ? w2 : w3;
  int off = comp * (128 * 256) + p * 256 + q;
  unsigned short v;
  if (*flagp) { v = ((const unsigned short*)W)[off]; if (neg) v ^= 0x8000u; }
  else        { float f = ((const float*)W)[off]; if (neg) f = -f; v = f2b(f); }
  WXT[idx] = v;
}

__global__ void expand_h_k(const void* w0, const void* w1, const void* w2, const void* w3,
                           const int* __restrict__ flagp, unsigned short* __restrict__ WHT) {
  int idx = blockIdx.x * 256 + threadIdx.x;   // < NCOL*HDIM (exact grid)
  int n = idx >> 10, k = idx & 1023;
  int j = n >> 2, g = n & 3;
  int rb = k >> 8, p = k & 255;               // HDIM/4 = 256
  int cb = j >> 8, q = j & 255;
  int comp = rb ^ cb;
  int neg = (rb & 1) && !(cb & 1);
  const void* W = (g == 0) ? w0 : (g == 1) ? w1 : (g == 2) ? w2 : w3;
  int off = comp * (256 * 256) + p * 256 + q;
  unsigned short v;
  if (*flagp) { v = ((const unsigned short*)W)[off]; if (neg) v ^= 0x8000u; }
  else        { float f = ((const float*)W)[off]; if (neg) f = -f; v = f2b(f); }
  WHT[idx] = v;
}

__global__ void bias_k(const void* b0, const void* b1, const void* b2, const void* b3,
                       const int* __restrict__ flagp, float* __restrict__ biasI) {
  int idx = blockIdx.x * 256 + threadIdx.x;   // < NCOL (exact grid)
  int j = idx >> 2, g = idx & 3;
  const void* B = (g == 0) ? b0 : (g == 1) ? b1 : (g == 2) ? b2 : b3;
  biasI[idx] = (*flagp) ? b2f(((const unsigned short*)B)[j]) : ((const float*)B)[j];
}

// ---- Phase B: 128-step recurrence with fused x-GEMM. Cooperative 256x256. ----
// Block owns 16 N-cols = hidden units j0..j0+3 x 4 gates. Weight slabs in LDS.
__global__ void __launch_bounds__(256) phaseB_k(const unsigned short* __restrict__ xbf,
                                                const unsigned short* __restrict__ WXT,
                                                const unsigned short* __restrict__ WHT,
                                                const float* __restrict__ biasI,
                                                unsigned short* __restrict__ h0,
                                                unsigned short* __restrict__ h1,
                                                float* __restrict__ cbuf) {
  __shared__ unsigned short Wh[16][1032];     // 16 n-cols x 1024 k (+8 pad) : 33.0 KB
  __shared__ unsigned short Wx[16][520];      // 16 n-cols x  512 k (+8 pad) : 16.6 KB
  __shared__ float Pl[4][16][16];             // per-wave 16x16 f32 staging  :  4.0 KB
  int tid = threadIdx.x;
  int n0 = blockIdx.x * 16;
  int j0 = blockIdx.x * 4;
  for (int c = tid; c < 16 * 128; c += 256) {
    int row = c >> 7, ch = c & 127;
    *(uint4*)&Wh[row][ch * 8] = *(const uint4*)&WHT[(n0 + row) * HDIM + ch * 8];
  }
  for (int c = tid; c < 16 * 64; c += 256) {
    int row = c >> 6, ch = c & 63;
    *(uint4*)&Wx[row][ch * 8] = *(const uint4*)&WXT[(n0 + row) * FDIM + ch * 8];
  }
  cg::grid_group grid = cg::this_grid();
  __syncthreads();
  int w = tid >> 6, lane = tid & 63;
  int col = lane & 15, quad = lane >> 4;
  int brow = w * 16 + col;                    // batch row (A-operand m AND elementwise b)
  int jl = quad;                              // hidden sub-unit for elementwise
  const unsigned short* whp = &Wh[col][quad * 8];
  const unsigned short* wxp = &Wx[col][quad * 8];
  float4 bv = *(const float4*)&biasI[n0 + jl * 4];  // gate biases of unit j0+jl
  for (int t = 0; t < T_STEPS; ++t) {
    const unsigned short* hin = (t & 1) ? h1 : h0;
    unsigned short*      hout = (t & 1) ? h0 : h1;
    fv4 acc0 = {0.f, 0.f, 0.f, 0.f};
    fv4 acc1 = {0.f, 0.f, 0.f, 0.f};
    const unsigned short* hrow = hin + brow * HDIM + quad * 8;
#pragma unroll 4
    for (int k0 = 0; k0 < HDIM; k0 += 64) {
      bfv8 a0 = *(const bfv8*)(hrow + k0);
      bfv8 b0 = *(const bfv8*)(whp + k0);
      bfv8 a1 = *(const bfv8*)(hrow + k0 + 32);
      bfv8 b1 = *(const bfv8*)(whp + k0 + 32);
      acc0 = __builtin_amdgcn_mfma_f32_16x16x32_bf16(a0, b0, acc0, 0, 0, 0);
      acc1 = __builtin_amdgcn_mfma_f32_16x16x32_bf16(a1, b1, acc1, 0, 0, 0);
    }
    const unsigned short* xrow = xbf + (t * BATCH + brow) * FDIM + quad * 8;
#pragma unroll 4
    for (int k0 = 0; k0 < FDIM; k0 += 64) {
      bfv8 a0 = *(const bfv8*)(xrow + k0);
      bfv8 b0 = *(const bfv8*)(wxp + k0);
      bfv8 a1 = *(const bfv8*)(xrow + k0 + 32);
      bfv8 b1 = *(const bfv8*)(wxp + k0 + 32);
      acc0 = __builtin_amdgcn_mfma_f32_16x16x32_bf16(a0, b0, acc0, 0, 0, 0);
      acc1 = __builtin_amdgcn_mfma_f32_16x16x32_bf16(a1, b1, acc1, 0, 0, 0);
    }
    fv4 acc = acc0 + acc1;
#pragma unroll
    for (int r = 0; r < 4; ++r) Pl[w][quad * 4 + r][col] = acc[r];  // C/D: row=quad*4+r, col=lane&15
    __syncthreads();
    float4 pv = *(const float4*)&Pl[w][col][jl * 4];  // (b_local=col, 4 gates of unit j0+jl)
    int cidx = brow * HDIM + j0 + jl;
    float cp = cbuf[cidx];
    float fg = sigm(pv.x + bv.x);
    float ig = sigm(pv.y + bv.y);
    float og = sigm(pv.z + bv.z);
    float av = pv.w + bv.w;
    float cn = ig * tanh_f(av) + fg * cp;
    float hn = og * tanh_f(cn);
    cbuf[cidx] = cn;
    hout[cidx] = f2b(hn);
    grid.sync();                              // h[t+1] visible to all blocks; also block barrier for Pl
  }
}

// ---- Phase C: out = h @ fco_W + fco_b ----
__global__ void phaseC_k(const unsigned short* __restrict__ h,
                         const void* __restrict__ fw, const void* __restrict__ fb,
                         const int* __restrict__ flagp, void* __restrict__ out) {
  int idx = blockIdx.x * 256 + threadIdx.x;
  if (idx >= BATCH * NCLS) return;
  int b = idx / NCLS, cc = idx - b * NCLS;
  const unsigned short* hr = h + b * HDIM;
  float acc = 0.f;
  if (*flagp) {
    const unsigned short* fwp = (const unsigned short*)fw;
    for (int k = 0; k < HDIM; ++k)
      acc = fmaf(b2f(hr[k]), b2f(fwp[k * NCLS + cc]), acc);
    acc += b2f(((const unsigned short*)fb)[cc]);
    ((unsigned short*)out)[idx] = f2b(acc);
  } else {
    const float* fwp = (const float*)fw;
    for (int k = 0; k < HDIM; ++k)
      acc = fmaf(b2f(hr[k]), fwp[k * NCLS + cc], acc);
    acc += ((const float*)fb)[cc];
    ((float*)out)[idx] = acc;
  }
}

extern "C" void kernel_launch(void* const* d_in, const int* in_sizes, int n_in,
                              void* d_out, int out_size, void* d_ws, size_t ws_size,
                              hipStream_t stream) {
  const void* x   = d_in[0];
  const void* wfx = d_in[1];  const void* bfv = d_in[2];  const void* wfh = d_in[3];
  const void* wix = d_in[4];  const void* biv = d_in[5];  const void* wih = d_in[6];
  const void* wox = d_in[7];  const void* bov = d_in[8];  const void* woh = d_in[9];
  const void* wcx = d_in[10]; const void* bcv = d_in[11]; const void* wch = d_in[12];
  const void* fcw = d_in[13]; const void* fcb = d_in[14];

  char* ws = (char*)d_ws;
  int*            flag  = (int*)           (ws);                 // 256 B slot
  unsigned short* WXT   = (unsigned short*)(ws + 256);           // 4 MB
  unsigned short* WHT   = (unsigned short*)(ws + 4194560);       // 8 MB
  float*          biasI = (float*)         (ws + 12583168);      // 16 KB
  unsigned short* xbf   = (unsigned short*)(ws + 12599552);      // 8 MB
  unsigned short* h0    = (unsigned short*)(ws + 20988160);      // 128 KB
  unsigned short* h1    = (unsigned short*)(ws + 21119232);      // 128 KB
  float*          cbuf  = (float*)         (ws + 21250304);      // 256 KB -> total ~21.5 MB

  detect_k<<<1, 256, 0, stream>>>((const unsigned short*)x, flag);
  convert_x_k<<<(T_STEPS * BATCH * FDIM) / 256, 256, 0, stream>>>(x, flag, xbf);
  expand_x_k<<<(NCOL * FDIM) / 256, 256, 0, stream>>>(wfx, wix, wox, wcx, flag, WXT);
  expand_h_k<<<(NCOL * HDIM) / 256, 256, 0, stream>>>(wfh, wih, woh, wch, flag, WHT);
  bias_k<<<NCOL / 256, 256, 0, stream>>>(bfv, biv, bov, bcv, flag, biasI);
  hipMemsetAsync(h0, 0, 131072 + 131072 + 262144, stream);       // h0, h1, cbuf

  const unsigned short* p_x = xbf;
  const unsigned short* p_wx = WXT;
  const unsigned short* p_wh = WHT;
  const float* p_bi = biasI;
  unsigned short* p_h0 = h0;
  unsigned short* p_h1 = h1;
  float* p_cb = cbuf;
  void* kargs[] = { (void*)&p_x, (void*)&p_wx, (void*)&p_wh, (void*)&p_bi,
                    (void*)&p_h0, (void*)&p_h1, (void*)&p_cb };
  hipLaunchCooperativeKernel((void*)phaseB_k, dim3(256), dim3(256), kargs, 0, stream);

  // final h is in h0 (last write at t=127, odd -> hout = h0)
  phaseC_k<<<(BATCH * NCLS + 255) / 256, 256, 0, stream>>>(h0, fcw, fcb, flag, d_out);
}

// Round 3
// 3870.319 us; speedup vs baseline: 1.2728x; 1.2728x over previous
//
#include <hip/hip_runtime.h>
#include <hip/hip_cooperative_groups.h>

typedef short bfv8 __attribute__((ext_vector_type(8)));  // 8 x bf16 (4 VGPRs)
typedef float fv4  __attribute__((ext_vector_type(4)));  // 4 x f32 accum
typedef unsigned long long u64;

#define T_STEPS 128
#define BATCH   64
#define FDIM    512
#define HDIM    1024
#define NCOL    4096   // 4*HDIM, gate-interleaved: n = j*4 + g (g: 0=f,1=i,2=o,3=c)
#define NCLS    513
#define NBLK    256

static __device__ __forceinline__ float b2f(unsigned short u) {
  union { unsigned int i; float f; } v; v.i = ((unsigned int)u) << 16; return v.f;
}
static __device__ __forceinline__ unsigned short f2b(float f) {
  union { float f; unsigned int i; } v; v.f = f;
  unsigned int r = v.i + 0x7FFFu + ((v.i >> 16) & 1u);   // RNE
  return (unsigned short)(r >> 16);
}
static __device__ __forceinline__ float sigm(float x) { return 1.0f / (1.0f + __expf(-x)); }
static __device__ __forceinline__ float tanh_f(float x) {
  float e = __expf(-2.0f * fabsf(x));
  float t = (1.0f - e) / (1.0f + e);
  return x >= 0.0f ? t : -t;
}

// ---- dtype detector: bf16 mode iff even-index ushorts look like bf16 N(0,1) ----
__global__ void detect_k(const unsigned short* __restrict__ xr, int* __restrict__ flag) {
  __shared__ int cnt;
  if (threadIdx.x == 0) cnt = 0;
  __syncthreads();
  int local = 0;
  for (int s = 0; s < 4; ++s) {
    int i = threadIdx.x + 256 * s;
    unsigned short u = xr[2 * i];
    int e = (u >> 7) & 0xFF;
    if (e >= 112 && e <= 131) local++;
  }
  atomicAdd(&cnt, local);
  __syncthreads();
  if (threadIdx.x == 0) *flag = (cnt >= 512) ? 1 : 0;
}

// ---- x -> bf16 (copy or convert) ----
__global__ void convert_x_k(const void* __restrict__ x, const int* __restrict__ flagp,
                            unsigned short* __restrict__ xbf) {
  int idx = blockIdx.x * 256 + threadIdx.x;
  if (*flagp) xbf[idx] = ((const unsigned short*)x)[idx];
  else        xbf[idx] = f2b(((const float*)x)[idx]);
}

// Tessarine block table: comp = rb ^ cb ; sign = - iff (rb odd) && (cb even).
__global__ void expand_x_k(const void* w0, const void* w1, const void* w2, const void* w3,
                           const int* __restrict__ flagp, unsigned short* __restrict__ WXT) {
  int idx = blockIdx.x * 256 + threadIdx.x;
  int n = idx >> 9, k = idx & 511;
  int j = n >> 2, g = n & 3;
  int rb = k >> 7, p = k & 127;
  int cb = j >> 8, q = j & 255;
  int comp = rb ^ cb;
  int neg = (rb & 1) && !(cb & 1);
  const void* W = (g == 0) ? w0 : (g == 1) ? w1 : (g == 2) ? w2 : w3;
  int off = comp * (128 * 256) + p * 256 + q;
  unsigned short v;
  if (*flagp) { v = ((const unsigned short*)W)[off]; if (neg) v ^= 0x8000u; }
  else        { float f = ((const float*)W)[off]; if (neg) f = -f; v = f2b(f); }
  WXT[idx] = v;
}

__global__ void expand_h_k(const void* w0, const void* w1, const void* w2, const void* w3,
                           const int* __restrict__ flagp, unsigned short* __restrict__ WHT) {
  int idx = blockIdx.x * 256 + threadIdx.x;
  int n = idx >> 10, k = idx & 1023;
  int j = n >> 2, g = n & 3;
  int rb = k >> 8, p = k & 255;
  int cb = j >> 8, q = j & 255;
  int comp = rb ^ cb;
  int neg = (rb & 1) && !(cb & 1);
  const void* W = (g == 0) ? w0 : (g == 1) ? w1 : (g == 2) ? w2 : w3;
  int off = comp * (256 * 256) + p * 256 + q;
  unsigned short v;
  if (*flagp) { v = ((const unsigned short*)W)[off]; if (neg) v ^= 0x8000u; }
  else        { float f = ((const float*)W)[off]; if (neg) f = -f; v = f2b(f); }
  WHT[idx] = v;
}

__global__ void bias_k(const void* b0, const void* b1, const void* b2, const void* b3,
                       const int* __restrict__ flagp, float* __restrict__ biasI) {
  int idx = blockIdx.x * 256 + threadIdx.x;
  int j = idx >> 2, g = idx & 3;
  const void* B = (g == 0) ? b0 : (g == 1) ? b1 : (g == 2) ? b2 : b3;
  biasI[idx] = (*flagp) ? b2f(((const unsigned short*)B)[j]) : ((const float*)B)[j];
}

// ---- Phase B: 128-step recurrence, custom IF$-level barrier (no L2 flush). ----
// Block owns 16 N-cols = hidden units j0..j0+3 x 4 gates. Weight slabs in LDS.
// h exchange: agent-scope atomic stores (write-through IF$) + agent-scope atomic
// loads (L2-bypass) -> no cache maintenance needed. c is thread-private.
__global__ void __launch_bounds__(256) phaseB_k(const unsigned short* __restrict__ xbf,
                                                const unsigned short* __restrict__ WXT,
                                                const unsigned short* __restrict__ WHT,
                                                const float* __restrict__ biasI,
                                                unsigned short* __restrict__ h0,
                                                unsigned short* __restrict__ h1,
                                                int* __restrict__ cnt) {
  __shared__ unsigned short Wh[16][1032];     // 16 n-cols x 1024 k (+8 pad)
  __shared__ unsigned short Wx[16][520];      // 16 n-cols x  512 k (+8 pad)
  __shared__ float Pl[4][16][16];             // per-wave 16x16 f32 staging
  int tid = threadIdx.x;
  int n0 = blockIdx.x * 16;
  int j0 = blockIdx.x * 4;
  for (int c = tid; c < 16 * 128; c += 256) {
    int row = c >> 7, ch = c & 127;
    *(uint4*)&Wh[row][ch * 8] = *(const uint4*)&WHT[(n0 + row) * HDIM + ch * 8];
  }
  for (int c = tid; c < 16 * 64; c += 256) {
    int row = c >> 6, ch = c & 63;
    *(uint4*)&Wx[row][ch * 8] = *(const uint4*)&WXT[(n0 + row) * FDIM + ch * 8];
  }
  __syncthreads();
  int w = tid >> 6, lane = tid & 63;
  int col = lane & 15, quad = lane >> 4;
  int brow = w * 16 + col;                    // batch row (A-operand m AND elementwise b)
  int jl = quad;                              // hidden sub-unit for elementwise
  const unsigned short* whp = &Wh[col][quad * 8];
  const unsigned short* wxp = &Wx[col][quad * 8];
  float4 bv = *(const float4*)&biasI[n0 + jl * 4];
  float creg = 0.0f;                          // c state is thread-private
  for (int t = 0; t < T_STEPS; ++t) {
    const unsigned short* hin = (t & 1) ? h1 : h0;
    unsigned short*      hout = (t & 1) ? h0 : h1;
    // Batch-issue all 64 x 8B h-loads (L2-bypass, IF$-coherent), pipelined.
    const u64* hq = (const u64*)(hin + brow * HDIM + quad * 8);
    u64 hreg[64];
#pragma unroll
    for (int f = 0; f < 32; ++f) {
      hreg[2 * f]     = __hip_atomic_load((u64*)(hq + f * 8),     __ATOMIC_RELAXED, __HIP_MEMORY_SCOPE_AGENT);
      hreg[2 * f + 1] = __hip_atomic_load((u64*)(hq + f * 8 + 1), __ATOMIC_RELAXED, __HIP_MEMORY_SCOPE_AGENT);
    }
    fv4 acc0 = {0.f, 0.f, 0.f, 0.f};
    fv4 acc1 = {0.f, 0.f, 0.f, 0.f};
    // x-GEMM first (plain L2-cached loads) while h loads are in flight.
    const unsigned short* xrow = xbf + (t * BATCH + brow) * FDIM + quad * 8;
#pragma unroll 4
    for (int k0 = 0; k0 < FDIM; k0 += 64) {
      bfv8 a0 = *(const bfv8*)(xrow + k0);
      bfv8 b0 = *(const bfv8*)(wxp + k0);
      bfv8 a1 = *(const bfv8*)(xrow + k0 + 32);
      bfv8 b1 = *(const bfv8*)(wxp + k0 + 32);
      acc0 = __builtin_amdgcn_mfma_f32_16x16x32_bf16(a0, b0, acc0, 0, 0, 0);
      acc1 = __builtin_amdgcn_mfma_f32_16x16x32_bf16(a1, b1, acc1, 0, 0, 0);
    }
    // h-GEMM from registers + LDS weights.
#pragma unroll 4
    for (int f = 0; f < 32; f += 2) {
      union { u64 q[2]; bfv8 v; } ua, ub;
      ua.q[0] = hreg[2 * f];     ua.q[1] = hreg[2 * f + 1];
      ub.q[0] = hreg[2 * f + 2]; ub.q[1] = hreg[2 * f + 3];
      bfv8 b0 = *(const bfv8*)(whp + f * 32);
      bfv8 b1 = *(const bfv8*)(whp + f * 32 + 32);
      acc0 = __builtin_amdgcn_mfma_f32_16x16x32_bf16(ua.v, b0, acc0, 0, 0, 0);
      acc1 = __builtin_amdgcn_mfma_f32_16x16x32_bf16(ub.v, b1, acc1, 0, 0, 0);
    }
    fv4 acc = acc0 + acc1;
#pragma unroll
    for (int r = 0; r < 4; ++r) Pl[w][quad * 4 + r][col] = acc[r];  // D: row=quad*4+r, col=lane&15
    __syncthreads();
    float4 pv = *(const float4*)&Pl[w][col][jl * 4];  // (b_local=col, 4 gates of unit j0+jl)
    float fg = sigm(pv.x + bv.x);
    float ig = sigm(pv.y + bv.y);
    float og = sigm(pv.z + bv.z);
    float av = pv.w + bv.w;
    float cn = ig * tanh_f(av) + fg * creg;
    float hn = og * tanh_f(cn);
    creg = cn;
    // Pack 4 consecutive j (quad 0..3) via shuffles -> one 8B write-through store.
    unsigned int u = f2b(hn);
    unsigned int a0 = __shfl((int)u, col, 64);
    unsigned int a1 = __shfl((int)u, col + 16, 64);
    unsigned int a2 = __shfl((int)u, col + 32, 64);
    unsigned int a3 = __shfl((int)u, col + 48, 64);
    if (quad == 0) {
      u64 pk = (u64)(a0 & 0xFFFFu) | ((u64)(a1 & 0xFFFFu) << 16)
             | ((u64)(a2 & 0xFFFFu) << 32) | ((u64)(a3 & 0xFFFFu) << 48);
      __hip_atomic_store((u64*)(hout + brow * HDIM + j0), pk,
                         __ATOMIC_RELAXED, __HIP_MEMORY_SCOPE_AGENT);
    }
    __builtin_amdgcn_s_waitcnt(0);            // drain this wave's stores to IF$
    __syncthreads();                          // all waves' stores drained (vmcnt0 before barrier)
    if (tid == 0) {
      __hip_atomic_fetch_add(&cnt[t], 1, __ATOMIC_RELAXED, __HIP_MEMORY_SCOPE_AGENT);
      while (__hip_atomic_load(&cnt[t], __ATOMIC_RELAXED, __HIP_MEMORY_SCOPE_AGENT) < NBLK)
        __builtin_amdgcn_s_sleep(1);
    }
    __syncthreads();
  }
}

// ---- Phase C: out = h @ fco_W + fco_b ----
__global__ void phaseC_k(const unsigned short* __restrict__ h,
                         const void* __restrict__ fw, const void* __restrict__ fb,
                         const int* __restrict__ flagp, void* __restrict__ out) {
  int idx = blockIdx.x * 256 + threadIdx.x;
  if (idx >= BATCH * NCLS) return;
  int b = idx / NCLS, cc = idx - b * NCLS;
  const unsigned short* hr = h + b * HDIM;
  float acc = 0.f;
  if (*flagp) {
    const unsigned short* fwp = (const unsigned short*)fw;
    for (int k = 0; k < HDIM; ++k)
      acc = fmaf(b2f(hr[k]), b2f(fwp[k * NCLS + cc]), acc);
    acc += b2f(((const unsigned short*)fb)[cc]);
    ((unsigned short*)out)[idx] = f2b(acc);
  } else {
    const float* fwp = (const float*)fw;
    for (int k = 0; k < HDIM; ++k)
      acc = fmaf(b2f(hr[k]), fwp[k * NCLS + cc], acc);
    acc += ((const float*)fb)[cc];
    ((float*)out)[idx] = acc;
  }
}

extern "C" void kernel_launch(void* const* d_in, const int* in_sizes, int n_in,
                              void* d_out, int out_size, void* d_ws, size_t ws_size,
                              hipStream_t stream) {
  const void* x   = d_in[0];
  const void* wfx = d_in[1];  const void* bfv = d_in[2];  const void* wfh = d_in[3];
  const void* wix = d_in[4];  const void* biv = d_in[5];  const void* wih = d_in[6];
  const void* wox = d_in[7];  const void* bov = d_in[8];  const void* woh = d_in[9];
  const void* wcx = d_in[10]; const void* bcv = d_in[11]; const void* wch = d_in[12];
  const void* fcw = d_in[13]; const void* fcb = d_in[14];

  char* ws = (char*)d_ws;
  int*            flag  = (int*)           (ws);                 // 256 B slot
  unsigned short* WXT   = (unsigned short*)(ws + 256);           // 4 MB
  unsigned short* WHT   = (unsigned short*)(ws + 4194560);       // 8 MB
  float*          biasI = (float*)         (ws + 12583168);      // 16 KB
  unsigned short* xbf   = (unsigned short*)(ws + 12599552);      // 8 MB
  unsigned short* h0    = (unsigned short*)(ws + 20988160);      // 128 KB
  unsigned short* h1    = (unsigned short*)(ws + 21119232);      // 128 KB
  int*            cnt   = (int*)           (ws + 21250304);      // 512 B -> total ~21.25 MB

  detect_k<<<1, 256, 0, stream>>>((const unsigned short*)x, flag);
  convert_x_k<<<(T_STEPS * BATCH * FDIM) / 256, 256, 0, stream>>>(x, flag, xbf);
  expand_x_k<<<(NCOL * FDIM) / 256, 256, 0, stream>>>(wfx, wix, wox, wcx, flag, WXT);
  expand_h_k<<<(NCOL * HDIM) / 256, 256, 0, stream>>>(wfh, wih, woh, wch, flag, WHT);
  bias_k<<<NCOL / 256, 256, 0, stream>>>(bfv, biv, bov, bcv, flag, biasI);
  hipMemsetAsync(h0, 0, 131072 + 131072 + 512, stream);          // h0, h1, cnt

  const unsigned short* p_x = xbf;
  const unsigned short* p_wx = WXT;
  const unsigned short* p_wh = WHT;
  const float* p_bi = biasI;
  unsigned short* p_h0 = h0;
  unsigned short* p_h1 = h1;
  int* p_cn = cnt;
  void* kargs[] = { (void*)&p_x, (void*)&p_wx, (void*)&p_wh, (void*)&p_bi,
                    (void*)&p_h0, (void*)&p_h1, (void*)&p_cn };
  hipLaunchCooperativeKernel((void*)phaseB_k, dim3(NBLK), dim3(256), kargs, 0, stream);

  // final h is in h0 (last write at t=127, odd -> hout = h0)
  phaseC_k<<<(BATCH * NCLS + 255) / 256, 256, 0, stream>>>(h0, fcw, fcb, flag, d_out);
}

// Round 4
// 2983.056 us; speedup vs baseline: 1.6514x; 1.2974x over previous
//
#include <hip/hip_runtime.h>
#include <hip/hip_cooperative_groups.h>

typedef short bfv8 __attribute__((ext_vector_type(8)));  // 8 x bf16 (4 VGPRs)
typedef float fv4  __attribute__((ext_vector_type(4)));  // 4 x f32 accum
typedef unsigned long long u64;

#define T_STEPS 128
#define BATCH   64
#define FDIM    512
#define HDIM    1024
#define NCOL    4096   // 4*HDIM, gate-interleaved: n = j*4 + g (g: 0=f,1=i,2=o,3=c)
#define NCLS    513
#define NBLK    256
#define HSLOT   65536  // elements per h ring slot (64 x 1024)

static __device__ __forceinline__ float b2f(unsigned short u) {
  union { unsigned int i; float f; } v; v.i = ((unsigned int)u) << 16; return v.f;
}
static __device__ __forceinline__ unsigned short f2b(float f) {
  union { float f; unsigned int i; } v; v.f = f;
  unsigned int r = v.i + 0x7FFFu + ((v.i >> 16) & 1u);   // RNE
  return (unsigned short)(r >> 16);
}
static __device__ __forceinline__ float sigm(float x) { return 1.0f / (1.0f + __expf(-x)); }
static __device__ __forceinline__ float tanh_f(float x) {
  float e = __expf(-2.0f * fabsf(x));
  float t = (1.0f - e) / (1.0f + e);
  return x >= 0.0f ? t : -t;
}

// ---- dtype detector: bf16 mode iff even-index ushorts look like bf16 N(0,1) ----
__global__ void detect_k(const unsigned short* __restrict__ xr, int* __restrict__ flag) {
  __shared__ int cnt;
  if (threadIdx.x == 0) cnt = 0;
  __syncthreads();
  int local = 0;
  for (int s = 0; s < 4; ++s) {
    int i = threadIdx.x + 256 * s;
    unsigned short u = xr[2 * i];
    int e = (u >> 7) & 0xFF;
    if (e >= 112 && e <= 131) local++;
  }
  atomicAdd(&cnt, local);
  __syncthreads();
  if (threadIdx.x == 0) *flag = (cnt >= 512) ? 1 : 0;
}

// ---- x -> bf16 (copy or convert) ----
__global__ void convert_x_k(const void* __restrict__ x, const int* __restrict__ flagp,
                            unsigned short* __restrict__ xbf) {
  int idx = blockIdx.x * 256 + threadIdx.x;
  if (*flagp) xbf[idx] = ((const unsigned short*)x)[idx];
  else        xbf[idx] = f2b(((const float*)x)[idx]);
}

// Tessarine block table: comp = rb ^ cb ; sign = - iff (rb odd) && (cb even).
__global__ void expand_x_k(const void* w0, const void* w1, const void* w2, const void* w3,
                           const int* __restrict__ flagp, unsigned short* __restrict__ WXT) {
  int idx = blockIdx.x * 256 + threadIdx.x;
  int n = idx >> 9, k = idx & 511;
  int j = n >> 2, g = n & 3;
  int rb = k >> 7, p = k & 127;
  int cb = j >> 8, q = j & 255;
  int comp = rb ^ cb;
  int neg = (rb & 1) && !(cb & 1);
  const void* W = (g == 0) ? w0 : (g == 1) ? w1 : (g == 2) ? w2 : w3;
  int off = comp * (128 * 256) + p * 256 + q;
  unsigned short v;
  if (*flagp) { v = ((const unsigned short*)W)[off]; if (neg) v ^= 0x8000u; }
  else        { float f = ((const float*)W)[off]; if (neg) f = -f; v = f2b(f); }
  WXT[idx] = v;
}

__global__ void expand_h_k(const void* w0, const void* w1, const void* w2, const void* w3,
                           const int* __restrict__ flagp, unsigned short* __restrict__ WHT) {
  int idx = blockIdx.x * 256 + threadIdx.x;
  int n = idx >> 10, k = idx & 1023;
  int j = n >> 2, g = n & 3;
  int rb = k >> 8, p = k & 255;
  int cb = j >> 8, q = j & 255;
  int comp = rb ^ cb;
  int neg = (rb & 1) && !(cb & 1);
  const void* W = (g == 0) ? w0 : (g == 1) ? w1 : (g == 2) ? w2 : w3;
  int off = comp * (256 * 256) + p * 256 + q;
  unsigned short v;
  if (*flagp) { v = ((const unsigned short*)W)[off]; if (neg) v ^= 0x8000u; }
  else        { float f = ((const float*)W)[off]; if (neg) f = -f; v = f2b(f); }
  WHT[idx] = v;
}

__global__ void bias_k(const void* b0, const void* b1, const void* b2, const void* b3,
                       const int* __restrict__ flagp, float* __restrict__ biasI) {
  int idx = blockIdx.x * 256 + threadIdx.x;
  int j = idx >> 2, g = idx & 3;
  const void* B = (g == 0) ? b0 : (g == 1) ? b1 : (g == 2) ? b2 : b3;
  biasI[idx] = (*flagp) ? b2f(((const unsigned short*)B)[j]) : ((const float*)B)[j];
}

// ---- Phase B: 128-step recurrence. Ring-buffered h (fresh addresses each step
// -> plain cached loads can never be stale), agent-scope write-through stores,
// custom flat barrier. No cache maintenance anywhere. ----
__global__ void __launch_bounds__(256) phaseB_k(const unsigned short* __restrict__ xbf,
                                                const unsigned short* __restrict__ WXT,
                                                const unsigned short* __restrict__ WHT,
                                                const float* __restrict__ biasI,
                                                unsigned short* __restrict__ hring,
                                                int* __restrict__ cnt) {
  __shared__ unsigned short Wh[16][1032];     // 16 n-cols x 1024 k (+8 pad)
  __shared__ unsigned short Wx[16][520];      // 16 n-cols x  512 k (+8 pad)
  __shared__ float Pl[4][16][16];             // per-wave 16x16 f32 staging
  int tid = threadIdx.x;
  int n0 = blockIdx.x * 16;
  int j0 = blockIdx.x * 4;
  for (int c = tid; c < 16 * 128; c += 256) {
    int row = c >> 7, ch = c & 127;
    *(uint4*)&Wh[row][ch * 8] = *(const uint4*)&WHT[(n0 + row) * HDIM + ch * 8];
  }
  for (int c = tid; c < 16 * 64; c += 256) {
    int row = c >> 6, ch = c & 63;
    *(uint4*)&Wx[row][ch * 8] = *(const uint4*)&WXT[(n0 + row) * FDIM + ch * 8];
  }
  __syncthreads();
  int w = tid >> 6, lane = tid & 63;
  int col = lane & 15, quad = lane >> 4;
  int brow = w * 16 + col;                    // batch row (A-operand m AND elementwise b)
  int jl = quad;                              // hidden sub-unit for elementwise
  const unsigned short* whp = &Wh[col][quad * 8];
  const unsigned short* wxp = &Wx[col][quad * 8];
  float4 bv = *(const float4*)&biasI[n0 + jl * 4];
  float creg = 0.0f;                          // c state is thread-private
  for (int t = 0; t < T_STEPS; ++t) {
    const unsigned short* hin  = hring + (size_t)t * HSLOT;
    unsigned short*       hout = hring + (size_t)(t + 1) * HSLOT;
    // Stage this lane's 32 h-fragments with plain 16B loads (fresh lines -> IF$ fill).
    const uint4* hq = (const uint4*)(hin + brow * HDIM + quad * 8);
    uint4 hs[32];
#pragma unroll
    for (int f = 0; f < 32; ++f) hs[f] = hq[f * 4];   // stride 64 B between fragments
    fv4 acc0 = {0.f, 0.f, 0.f, 0.f};
    fv4 acc1 = {0.f, 0.f, 0.f, 0.f};
    // x-GEMM (L2-cached loads) while h fills are in flight.
    const unsigned short* xrow = xbf + (t * BATCH + brow) * FDIM + quad * 8;
#pragma unroll 4
    for (int k0 = 0; k0 < FDIM; k0 += 64) {
      bfv8 a0 = *(const bfv8*)(xrow + k0);
      bfv8 b0 = *(const bfv8*)(wxp + k0);
      bfv8 a1 = *(const bfv8*)(xrow + k0 + 32);
      bfv8 b1 = *(const bfv8*)(wxp + k0 + 32);
      acc0 = __builtin_amdgcn_mfma_f32_16x16x32_bf16(a0, b0, acc0, 0, 0, 0);
      acc1 = __builtin_amdgcn_mfma_f32_16x16x32_bf16(a1, b1, acc1, 0, 0, 0);
    }
    // h-GEMM from staged registers + LDS weights.
#pragma unroll 4
    for (int f = 0; f < 32; f += 2) {
      union { uint4 q; bfv8 v; } ua, ub;
      ua.q = hs[f];
      ub.q = hs[f + 1];
      bfv8 b0 = *(const bfv8*)(whp + f * 32);
      bfv8 b1 = *(const bfv8*)(whp + f * 32 + 32);
      acc0 = __builtin_amdgcn_mfma_f32_16x16x32_bf16(ua.v, b0, acc0, 0, 0, 0);
      acc1 = __builtin_amdgcn_mfma_f32_16x16x32_bf16(ub.v, b1, acc1, 0, 0, 0);
    }
    fv4 acc = acc0 + acc1;
#pragma unroll
    for (int r = 0; r < 4; ++r) Pl[w][quad * 4 + r][col] = acc[r];  // D: row=quad*4+r, col=lane&15
    __syncthreads();
    float4 pv = *(const float4*)&Pl[w][col][jl * 4];  // (b_local=col, 4 gates of unit j0+jl)
    float fg = sigm(pv.x + bv.x);
    float ig = sigm(pv.y + bv.y);
    float og = sigm(pv.z + bv.z);
    float av = pv.w + bv.w;
    float cn = ig * tanh_f(av) + fg * creg;
    float hn = og * tanh_f(cn);
    creg = cn;
    // Pack 4 consecutive j (quad 0..3) via shuffles -> one 8B write-through store.
    unsigned int u = f2b(hn);
    unsigned int a0 = __shfl((int)u, col, 64);
    unsigned int a1 = __shfl((int)u, col + 16, 64);
    unsigned int a2 = __shfl((int)u, col + 32, 64);
    unsigned int a3 = __shfl((int)u, col + 48, 64);
    if (quad == 0) {
      u64 pk = (u64)(a0 & 0xFFFFu) | ((u64)(a1 & 0xFFFFu) << 16)
             | ((u64)(a2 & 0xFFFFu) << 32) | ((u64)(a3 & 0xFFFFu) << 48);
      __hip_atomic_store((u64*)(hout + brow * HDIM + j0), pk,
                         __ATOMIC_RELAXED, __HIP_MEMORY_SCOPE_AGENT);
    }
    asm volatile("" ::: "memory");
    __builtin_amdgcn_s_waitcnt(0);            // drain write-through stores to IF$
    __syncthreads();                          // all waves in block drained
    if (tid == 0) {
      __hip_atomic_fetch_add(&cnt[t * 16], 1, __ATOMIC_RELAXED, __HIP_MEMORY_SCOPE_AGENT);
      while (__hip_atomic_load(&cnt[t * 16], __ATOMIC_RELAXED, __HIP_MEMORY_SCOPE_AGENT) < NBLK)
        __builtin_amdgcn_s_sleep(2);
    }
    __syncthreads();
    asm volatile("" ::: "memory");            // no load hoisting above the barrier
  }
}

// ---- Phase C: out = h @ fco_W + fco_b ----
__global__ void phaseC_k(const unsigned short* __restrict__ h,
                         const void* __restrict__ fw, const void* __restrict__ fb,
                         const int* __restrict__ flagp, void* __restrict__ out) {
  int idx = blockIdx.x * 256 + threadIdx.x;
  if (idx >= BATCH * NCLS) return;
  int b = idx / NCLS, cc = idx - b * NCLS;
  const unsigned short* hr = h + b * HDIM;
  float acc = 0.f;
  if (*flagp) {
    const unsigned short* fwp = (const unsigned short*)fw;
    for (int k = 0; k < HDIM; ++k)
      acc = fmaf(b2f(hr[k]), b2f(fwp[k * NCLS + cc]), acc);
    acc += b2f(((const unsigned short*)fb)[cc]);
    ((unsigned short*)out)[idx] = f2b(acc);
  } else {
    const float* fwp = (const float*)fw;
    for (int k = 0; k < HDIM; ++k)
      acc = fmaf(b2f(hr[k]), fwp[k * NCLS + cc], acc);
    acc += ((const float*)fb)[cc];
    ((float*)out)[idx] = acc;
  }
}

extern "C" void kernel_launch(void* const* d_in, const int* in_sizes, int n_in,
                              void* d_out, int out_size, void* d_ws, size_t ws_size,
                              hipStream_t stream) {
  const void* x   = d_in[0];
  const void* wfx = d_in[1];  const void* bfv = d_in[2];  const void* wfh = d_in[3];
  const void* wix = d_in[4];  const void* biv = d_in[5];  const void* wih = d_in[6];
  const void* wox = d_in[7];  const void* bov = d_in[8];  const void* woh = d_in[9];
  const void* wcx = d_in[10]; const void* bcv = d_in[11]; const void* wch = d_in[12];
  const void* fcw = d_in[13]; const void* fcb = d_in[14];

  char* ws = (char*)d_ws;
  int*            flag  = (int*)           (ws);                 // 256 B
  unsigned short* WXT   = (unsigned short*)(ws + 256);           // 4 MB
  unsigned short* WHT   = (unsigned short*)(ws + 4194560);       // 8 MB
  float*          biasI = (float*)         (ws + 12583168);      // 16 KB
  unsigned short* xbf   = (unsigned short*)(ws + 12599552);      // 8 MB
  unsigned short* hring = (unsigned short*)(ws + 20988160);      // 129 x 128 KB = 16.9 MB
  int*            cnt   = (int*)           (ws + 37896448);      // 8 KB -> total ~37.9 MB

  detect_k<<<1, 256, 0, stream>>>((const unsigned short*)x, flag);
  convert_x_k<<<(T_STEPS * BATCH * FDIM) / 256, 256, 0, stream>>>(x, flag, xbf);
  expand_x_k<<<(NCOL * FDIM) / 256, 256, 0, stream>>>(wfx, wix, wox, wcx, flag, WXT);
  expand_h_k<<<(NCOL * HDIM) / 256, 256, 0, stream>>>(wfh, wih, woh, wch, flag, WHT);
  bias_k<<<NCOL / 256, 256, 0, stream>>>(bfv, biv, bov, bcv, flag, biasI);
  hipMemsetAsync(hring, 0, 131072, stream);                      // h[0] = 0
  hipMemsetAsync(cnt, 0, 8192, stream);                          // barrier counters

  const unsigned short* p_x = xbf;
  const unsigned short* p_wx = WXT;
  const unsigned short* p_wh = WHT;
  const float* p_bi = biasI;
  unsigned short* p_hr = hring;
  int* p_cn = cnt;
  void* kargs[] = { (void*)&p_x, (void*)&p_wx, (void*)&p_wh, (void*)&p_bi,
                    (void*)&p_hr, (void*)&p_cn };
  hipLaunchCooperativeKernel((void*)phaseB_k, dim3(NBLK), dim3(256), kargs, 0, stream);

  // final h is ring slot 128
  phaseC_k<<<(BATCH * NCLS + 255) / 256, 256, 0, stream>>>(hring + 128 * HSLOT, fcw, fcb,
                                                           flag, d_out);
}